// Round 1
// baseline (389.973 us; speedup 1.0000x reference)
//
#include <hip/hip_runtime.h>
#include <hip/hip_bf16.h>
#include <hip/hip_fp16.h>
#include <cstdint>

#define NT      32768
#define DIN     256
#define DHID    1024
#define DOUT    256
#define NPLANES 8

typedef unsigned short u16;
typedef __attribute__((ext_vector_type(8))) _Float16 f16x8;
typedef __attribute__((ext_vector_type(4))) float    f32x4;

// ---------------- workspace layout (bytes) ----------------
#define WS_COUNTS   0                         // 8 ints
#define WS_CURSORS  64                        // 8 ints
#define WS_OFFSETS  128                       // 9 ints
#define WS_META     192                       // 1 int (tile count)
#define WS_TILEP    512                       // 264 ints
#define WS_TILEM    2048                      // 264 ints
#define WS_PERM     4096                      // NT ints
#define WS_XB       (WS_PERM + NT*4)          // NT*DIN f16
#define WS_W1B      (WS_XB  + NT*DIN*2)       // L*DHID*DIN f16
#define WS_W2B      (WS_W1B + NPLANES*DHID*DIN*2)
#define WS_HB       (WS_W2B + NPLANES*DOUT*DHID*2)  // NT*DHID f16

__device__ __forceinline__ u16 f2h_bits(float f) {
    __half h = __float2half(f);
    return *reinterpret_cast<u16*>(&h);
}

__device__ __forceinline__ void gl_lds16(const void* g, void* l) {
    __builtin_amdgcn_global_load_lds(
        (const __attribute__((address_space(1))) void*)g,
        (__attribute__((address_space(3))) void*)l,
        16, 0, 0);
}

// ---------------- bucketing ----------------
__global__ void init_k(int* ws_i) {
    int t = threadIdx.x;
    if (t < 24) ws_i[t] = 0;   // counts (0..7) + pad + cursors (16..23)
}

__global__ void count_k(const int* __restrict__ pidx, int* __restrict__ counts) {
    int i = blockIdx.x * blockDim.x + threadIdx.x;
    if (i < NT) atomicAdd(&counts[pidx[i]], 1);
}

__global__ void scan_k(const int* __restrict__ counts, int* __restrict__ offsets,
                       int* __restrict__ meta, int* __restrict__ tileP,
                       int* __restrict__ tileM) {
    if (threadIdx.x != 0 || blockIdx.x != 0) return;
    int off = 0, t = 0;
    for (int p = 0; p < NPLANES; ++p) {
        offsets[p] = off;
        int c = counts[p];
        for (int m = 0; m < c; m += 128) { tileP[t] = p; tileM[t] = m; ++t; }
        off += c;
    }
    offsets[NPLANES] = off;
    meta[0] = t;
}

__global__ void scatter_k(const int* __restrict__ pidx, const int* __restrict__ offsets,
                          int* __restrict__ cursors, int* __restrict__ perm) {
    int i = blockIdx.x * blockDim.x + threadIdx.x;
    if (i < NT) {
        int p = pidx[i];
        int pos = offsets[p] + atomicAdd(&cursors[p], 1);
        perm[pos] = i;
    }
}

// ---------------- f32 -> f16 convert (vectorized) ----------------
__global__ void cvt_k(const float* __restrict__ src, u16* __restrict__ dst, int n4) {
    int stride = gridDim.x * blockDim.x;
    for (int i = blockIdx.x * blockDim.x + threadIdx.x; i < n4; i += stride) {
        float4 v = reinterpret_cast<const float4*>(src)[i];
        ushort4 o;
        o.x = f2h_bits(v.x); o.y = f2h_bits(v.y);
        o.z = f2h_bits(v.z); o.w = f2h_bits(v.w);
        reinterpret_cast<ushort4*>(dst)[i] = o;
    }
}

// ---------------- grouped GEMM (128x128 tile, BK=64, 4 waves) ----------------
// LAYER1: A = xb gathered via perm, B = w1b[p] (DHID x DIN), out = gelu -> hb (f16, bucketed)
// LAYER2: A = hb contiguous,       B = w2b[p] (DOUT x DHID), out = f32 scattered via perm
template<bool LAYER1>
__global__ __launch_bounds__(256, 2) void gemm_k(
    const u16* __restrict__ A, const u16* __restrict__ Bw,
    const float* __restrict__ bias, const int* __restrict__ perm,
    const int* __restrict__ offsets, const int* __restrict__ meta,
    const int* __restrict__ tileP, const int* __restrict__ tileM,
    void* __restrict__ Out)
{
    constexpr int K  = LAYER1 ? DIN : DHID;
    constexpr int ND = LAYER1 ? DHID : DOUT;
    constexpr int BK = 64;
    constexpr int KT = K / BK;

    if ((int)blockIdx.y >= meta[0]) return;
    const int p   = tileP[blockIdx.y];
    const int m0  = tileM[blockIdx.y];
    const int off = offsets[p];
    const int cnt = offsets[p + 1] - off;
    const int n0  = blockIdx.x * 128;

    __shared__ __align__(16) u16 sA[128 * BK];
    __shared__ __align__(16) u16 sB[128 * BK];

    const int tid  = threadIdx.x;
    const int srow = tid >> 3;   // 0..31
    const int sch  = tid & 7;    // chunk slot 0..7 (16B each)

    // staging source pointers (global pre-swizzled so linear LDS dest ends up XOR-swizzled)
    const u16* aptr[4];
    const u16* bptr[4];
#pragma unroll
    for (int i = 0; i < 4; ++i) {
        int r  = i * 32 + srow;
        int gr = m0 + r; if (gr > cnt - 1) gr = cnt - 1;
        long arow = LAYER1 ? (long)perm[off + gr] * K : (long)(off + gr) * K;
        aptr[i] = A + arow + (size_t)((sch ^ (r & 7)) * 8);
        int br = i * 32 + srow;
        bptr[i] = Bw + ((long)p * ND + n0 + br) * K + (size_t)((sch ^ (br & 7)) * 8);
    }

    const int wave = tid >> 6;
    const int lane = tid & 63;
    const int wm   = (wave >> 1) * 64;
    const int wn   = (wave & 1) * 64;
    const int lm   = lane & 15;
    const int lk   = lane >> 4;   // 0..3

    f32x4 acc[4][4];
#pragma unroll
    for (int a = 0; a < 4; ++a)
#pragma unroll
        for (int b = 0; b < 4; ++b) acc[a][b] = (f32x4){0.f, 0.f, 0.f, 0.f};

    for (int kt = 0; kt < KT; ++kt) {
        const int k0 = kt * BK;
#pragma unroll
        for (int i = 0; i < 4; ++i) {
            gl_lds16(aptr[i] + k0, sA + i * 2048 + tid * 8);
            gl_lds16(bptr[i] + k0, sB + i * 2048 + tid * 8);
        }
        __syncthreads();   // drains vmcnt+lgkmcnt before barrier
#pragma unroll
        for (int kk = 0; kk < 2; ++kk) {
            f16x8 af[4], bfr[4];
#pragma unroll
            for (int mf = 0; mf < 4; ++mf) {
                int row = wm + mf * 16 + lm;
                int g   = kk * 4 + lk;
                af[mf] = *reinterpret_cast<const f16x8*>(sA + row * BK + ((g ^ (row & 7)) * 8));
            }
#pragma unroll
            for (int nf = 0; nf < 4; ++nf) {
                int row = wn + nf * 16 + lm;
                int g   = kk * 4 + lk;
                bfr[nf] = *reinterpret_cast<const f16x8*>(sB + row * BK + ((g ^ (row & 7)) * 8));
            }
#pragma unroll
            for (int mf = 0; mf < 4; ++mf)
#pragma unroll
                for (int nf = 0; nf < 4; ++nf)
                    acc[mf][nf] = __builtin_amdgcn_mfma_f32_16x16x32_f16(
                        af[mf], bfr[nf], acc[mf][nf], 0, 0, 0);
        }
        __syncthreads();
    }

    // epilogue: C/D layout col=lane&15, row=(lane>>4)*4+j
#pragma unroll
    for (int nf = 0; nf < 4; ++nf) {
        int col  = n0 + wn + nf * 16 + lm;
        float bb = bias[p * ND + col];
#pragma unroll
        for (int mf = 0; mf < 4; ++mf) {
            f32x4 v = acc[mf][nf];
#pragma unroll
            for (int j = 0; j < 4; ++j) {
                int ml = wm + mf * 16 + (lane >> 4) * 4 + j;
                int gr = m0 + ml;
                if (gr < cnt) {
                    float x = v[j] + bb;
                    if (LAYER1) {
                        float g = 0.5f * x * (1.0f + erff(x * 0.70710678118654752f));
                        ((u16*)Out)[(size_t)(off + gr) * DHID + col] = f2h_bits(g);
                    } else {
                        ((float*)Out)[(size_t)perm[off + gr] * DOUT + col] = x;
                    }
                }
            }
        }
    }
}

// ---------------- launch ----------------
extern "C" void kernel_launch(void* const* d_in, const int* in_sizes, int n_in,
                              void* d_out, int out_size, void* d_ws, size_t ws_size,
                              hipStream_t stream) {
    const float* x    = (const float*)d_in[0];
    const float* W1   = (const float*)d_in[1];
    const float* b1   = (const float*)d_in[2];
    const float* W2   = (const float*)d_in[3];
    const float* b2   = (const float*)d_in[4];
    const int*   pidx = (const int*)d_in[5];
    float*       out  = (float*)d_out;

    char* ws      = (char*)d_ws;
    int* counts   = (int*)(ws + WS_COUNTS);
    int* cursors  = (int*)(ws + WS_CURSORS);
    int* offsets  = (int*)(ws + WS_OFFSETS);
    int* meta     = (int*)(ws + WS_META);
    int* tileP    = (int*)(ws + WS_TILEP);
    int* tileM    = (int*)(ws + WS_TILEM);
    int* perm     = (int*)(ws + WS_PERM);
    u16* xb       = (u16*)(ws + WS_XB);
    u16* w1b      = (u16*)(ws + WS_W1B);
    u16* w2b      = (u16*)(ws + WS_W2B);
    u16* hb       = (u16*)(ws + WS_HB);

    init_k<<<1, 64, 0, stream>>>((int*)ws);
    count_k<<<NT / 256, 256, 0, stream>>>(pidx, counts);
    scan_k<<<1, 1, 0, stream>>>(counts, offsets, meta, tileP, tileM);
    scatter_k<<<NT / 256, 256, 0, stream>>>(pidx, offsets, cursors, perm);

    cvt_k<<<2048, 256, 0, stream>>>(x,  xb,  NT * DIN / 4);
    cvt_k<<<1024, 256, 0, stream>>>(W1, w1b, NPLANES * DHID * DIN / 4);
    cvt_k<<<1024, 256, 0, stream>>>(W2, w2b, NPLANES * DOUT * DHID / 4);

    gemm_k<true ><<<dim3(DHID / 128, 264, 1), 256, 0, stream>>>(
        xb, w1b, b1, perm, offsets, meta, tileP, tileM, (void*)hb);
    gemm_k<false><<<dim3(DOUT / 128, 264, 1), 256, 0, stream>>>(
        hb, w2b, b2, perm, offsets, meta, tileP, tileM, (void*)out);
}

// Round 2
// 150.057 us; speedup vs baseline: 2.5988x; 2.5988x over previous
//
#include <hip/hip_runtime.h>
#include <hip/hip_bf16.h>
#include <hip/hip_fp16.h>
#include <cstdint>

#define NT      32768
#define DIN     256
#define DHID    1024
#define DOUT    256
#define NPLANES 8
#define NBLK    (NT / 256)     // 128 bucketing blocks

typedef unsigned short u16;
typedef __attribute__((ext_vector_type(8))) _Float16 f16x8;
typedef __attribute__((ext_vector_type(4))) float    f32x4;

// ---------------- workspace layout (bytes) ----------------
#define WS_OFFSETS  0                          // 9 ints
#define WS_META     64                         // 1 int (tile count)
#define WS_TILEP    512                        // 264 ints
#define WS_TILEM    2048                       // 264 ints
#define WS_BLKHIST  4096                       // NBLK*8 ints (4 KB)
#define WS_BLKBASE  (WS_BLKHIST + NBLK*8*4)    // NBLK*8 ints
#define WS_PERM     (WS_BLKBASE + NBLK*8*4)    // NT ints
#define WS_XB       (WS_PERM + NT*4)           // NT*DIN f16
#define WS_W1B      (WS_XB  + NT*DIN*2)        // L*DHID*DIN f16
#define WS_W2B      (WS_W1B + NPLANES*DHID*DIN*2)
#define WS_HB       (WS_W2B + NPLANES*DOUT*DHID*2)  // NT*DHID f16

__device__ __forceinline__ u16 f2h_bits(float f) {
    __half h = __float2half(f);
    return *reinterpret_cast<u16*>(&h);
}

__device__ __forceinline__ void gl_lds16(const void* g, void* l) {
    __builtin_amdgcn_global_load_lds(
        (const __attribute__((address_space(1))) void*)g,
        (__attribute__((address_space(3))) void*)l,
        16, 0, 0);
}

// ---------------- bucketing (atomic-free, deterministic) ----------------
__global__ void hist_k(const int* __restrict__ pidx, int* __restrict__ blkhist) {
    __shared__ int cnt[NPLANES];
    const int t = threadIdx.x, lane = t & 63, wave = t >> 6;
    if (t < NPLANES) cnt[t] = 0;
    __syncthreads();
    const int p = pidx[blockIdx.x * 256 + t];
#pragma unroll
    for (int q = 0; q < NPLANES; ++q) {
        unsigned long long m = __ballot(p == q);
        if (p == q && __popcll(m & ((1ULL << lane) - 1)) == 0)
            atomicAdd(&cnt[q], __popcll(m));   // LDS atomic, 4/wavegroup
    }
    (void)wave;
    __syncthreads();
    if (t < NPLANES) blkhist[blockIdx.x * NPLANES + t] = cnt[t];
}

__global__ void scan_k(const int* __restrict__ blkhist, int* __restrict__ offsets,
                       int* __restrict__ blkbase, int* __restrict__ meta,
                       int* __restrict__ tileP, int* __restrict__ tileM) {
    __shared__ int tot[NPLANES];
    const int t = threadIdx.x;
    if (t < NPLANES) {
        int s = 0;
#pragma unroll 8
        for (int b = 0; b < NBLK; ++b) s += blkhist[b * NPLANES + t];
        tot[t] = s;
    }
    __syncthreads();
    if (t == 0) {
        int off = 0, tc = 0;
        for (int p = 0; p < NPLANES; ++p) {
            offsets[p] = off;
            for (int m = 0; m < tot[p]; m += 128) { tileP[tc] = p; tileM[tc] = m; ++tc; }
            off += tot[p];
        }
        offsets[NPLANES] = off;
        meta[0] = tc;
    }
    __syncthreads();
    if (t < NPLANES) {
        int run = offsets[t];
#pragma unroll 8
        for (int b = 0; b < NBLK; ++b) {
            blkbase[b * NPLANES + t] = run;
            run += blkhist[b * NPLANES + t];
        }
    }
}

__global__ void scatter_k(const int* __restrict__ pidx, const int* __restrict__ blkbase,
                          int* __restrict__ perm) {
    __shared__ int wcnt[4][NPLANES];
    __shared__ int wbase[4][NPLANES];
    const int t = threadIdx.x, lane = t & 63, wave = t >> 6;
    const int i = blockIdx.x * 256 + t;
    const int p = pidx[i];
    int rank = 0;
#pragma unroll
    for (int q = 0; q < NPLANES; ++q) {
        unsigned long long m = __ballot(p == q);
        if (lane == 0) wcnt[wave][q] = __popcll(m);
        if (p == q) rank = __popcll(m & ((1ULL << lane) - 1));
    }
    __syncthreads();
    if (t < NPLANES) {
        int run = blkbase[blockIdx.x * NPLANES + t];
#pragma unroll
        for (int w = 0; w < 4; ++w) { wbase[w][t] = run; run += wcnt[w][t]; }
    }
    __syncthreads();
    perm[wbase[wave][p] + rank] = i;   // blkbase already includes offsets[p]
}

// ---------------- f32 -> f16 convert (vectorized) ----------------
__global__ void cvt_k(const float* __restrict__ src, u16* __restrict__ dst, int n4) {
    int stride = gridDim.x * blockDim.x;
    for (int i = blockIdx.x * blockDim.x + threadIdx.x; i < n4; i += stride) {
        float4 v = reinterpret_cast<const float4*>(src)[i];
        ushort4 o;
        o.x = f2h_bits(v.x); o.y = f2h_bits(v.y);
        o.z = f2h_bits(v.z); o.w = f2h_bits(v.w);
        reinterpret_cast<ushort4*>(dst)[i] = o;
    }
}

// ---------------- grouped GEMM (128x128 tile, BK=64, 4 waves) ----------------
// LAYER1: A = xb gathered via perm, B = w1b[p] (DHID x DIN), out = gelu -> hb (f16, bucketed)
// LAYER2: A = hb contiguous,       B = w2b[p] (DOUT x DHID), out = f32 scattered via perm
template<bool LAYER1>
__global__ __launch_bounds__(256, 2) void gemm_k(
    const u16* __restrict__ A, const u16* __restrict__ Bw,
    const float* __restrict__ bias, const int* __restrict__ perm,
    const int* __restrict__ offsets, const int* __restrict__ meta,
    const int* __restrict__ tileP, const int* __restrict__ tileM,
    void* __restrict__ Out)
{
    constexpr int K  = LAYER1 ? DIN : DHID;
    constexpr int ND = LAYER1 ? DHID : DOUT;
    constexpr int BK = 64;
    constexpr int KT = K / BK;

    if ((int)blockIdx.y >= meta[0]) return;
    const int p   = tileP[blockIdx.y];
    const int m0  = tileM[blockIdx.y];
    const int off = offsets[p];
    const int cnt = offsets[p + 1] - off;
    const int n0  = blockIdx.x * 128;

    __shared__ __align__(16) u16 sA[128 * BK];
    __shared__ __align__(16) u16 sB[128 * BK];

    const int tid  = threadIdx.x;
    const int srow = tid >> 3;   // 0..31
    const int sch  = tid & 7;    // chunk slot 0..7 (16B each)

    // staging source pointers (global pre-swizzled so linear LDS dest ends up XOR-swizzled)
    const u16* aptr[4];
    const u16* bptr[4];
#pragma unroll
    for (int i = 0; i < 4; ++i) {
        int r  = i * 32 + srow;
        int gr = m0 + r; if (gr > cnt - 1) gr = cnt - 1;
        long arow = LAYER1 ? (long)perm[off + gr] * K : (long)(off + gr) * K;
        aptr[i] = A + arow + (size_t)((sch ^ (r & 7)) * 8);
        int br = i * 32 + srow;
        bptr[i] = Bw + ((long)p * ND + n0 + br) * K + (size_t)((sch ^ (br & 7)) * 8);
    }

    const int wave = tid >> 6;
    const int lane = tid & 63;
    const int wm   = (wave >> 1) * 64;
    const int wn   = (wave & 1) * 64;
    const int lm   = lane & 15;
    const int lk   = lane >> 4;   // 0..3

    f32x4 acc[4][4];
#pragma unroll
    for (int a = 0; a < 4; ++a)
#pragma unroll
        for (int b = 0; b < 4; ++b) acc[a][b] = (f32x4){0.f, 0.f, 0.f, 0.f};

    for (int kt = 0; kt < KT; ++kt) {
        const int k0 = kt * BK;
#pragma unroll
        for (int i = 0; i < 4; ++i) {
            gl_lds16(aptr[i] + k0, sA + i * 2048 + tid * 8);
            gl_lds16(bptr[i] + k0, sB + i * 2048 + tid * 8);
        }
        __syncthreads();   // drains vmcnt+lgkmcnt before barrier
#pragma unroll
        for (int kk = 0; kk < 2; ++kk) {
            f16x8 af[4], bfr[4];
#pragma unroll
            for (int mf = 0; mf < 4; ++mf) {
                int row = wm + mf * 16 + lm;
                int g   = kk * 4 + lk;
                af[mf] = *reinterpret_cast<const f16x8*>(sA + row * BK + ((g ^ (row & 7)) * 8));
            }
#pragma unroll
            for (int nf = 0; nf < 4; ++nf) {
                int row = wn + nf * 16 + lm;
                int g   = kk * 4 + lk;
                bfr[nf] = *reinterpret_cast<const f16x8*>(sB + row * BK + ((g ^ (row & 7)) * 8));
            }
#pragma unroll
            for (int mf = 0; mf < 4; ++mf)
#pragma unroll
                for (int nf = 0; nf < 4; ++nf)
                    acc[mf][nf] = __builtin_amdgcn_mfma_f32_16x16x32_f16(
                        af[mf], bfr[nf], acc[mf][nf], 0, 0, 0);
        }
        __syncthreads();
    }

    // epilogue: C/D layout col=lane&15, row=(lane>>4)*4+j
#pragma unroll
    for (int nf = 0; nf < 4; ++nf) {
        int col  = n0 + wn + nf * 16 + lm;
        float bb = bias[p * ND + col];
#pragma unroll
        for (int mf = 0; mf < 4; ++mf) {
            f32x4 v = acc[mf][nf];
#pragma unroll
            for (int j = 0; j < 4; ++j) {
                int ml = wm + mf * 16 + (lane >> 4) * 4 + j;
                int gr = m0 + ml;
                if (gr < cnt) {
                    float x = v[j] + bb;
                    if (LAYER1) {
                        float g = 0.5f * x * (1.0f + erff(x * 0.70710678118654752f));
                        ((u16*)Out)[(size_t)(off + gr) * DHID + col] = f2h_bits(g);
                    } else {
                        ((float*)Out)[(size_t)perm[off + gr] * DOUT + col] = x;
                    }
                }
            }
        }
    }
}

// ---------------- launch ----------------
extern "C" void kernel_launch(void* const* d_in, const int* in_sizes, int n_in,
                              void* d_out, int out_size, void* d_ws, size_t ws_size,
                              hipStream_t stream) {
    const float* x    = (const float*)d_in[0];
    const float* W1   = (const float*)d_in[1];
    const float* b1   = (const float*)d_in[2];
    const float* W2   = (const float*)d_in[3];
    const float* b2   = (const float*)d_in[4];
    const int*   pidx = (const int*)d_in[5];
    float*       out  = (float*)d_out;

    char* ws      = (char*)d_ws;
    int* offsets  = (int*)(ws + WS_OFFSETS);
    int* meta     = (int*)(ws + WS_META);
    int* tileP    = (int*)(ws + WS_TILEP);
    int* tileM    = (int*)(ws + WS_TILEM);
    int* blkhist  = (int*)(ws + WS_BLKHIST);
    int* blkbase  = (int*)(ws + WS_BLKBASE);
    int* perm     = (int*)(ws + WS_PERM);
    u16* xb       = (u16*)(ws + WS_XB);
    u16* w1b      = (u16*)(ws + WS_W1B);
    u16* w2b      = (u16*)(ws + WS_W2B);
    u16* hb       = (u16*)(ws + WS_HB);

    hist_k<<<NBLK, 256, 0, stream>>>(pidx, blkhist);
    scan_k<<<1, 64, 0, stream>>>(blkhist, offsets, blkbase, meta, tileP, tileM);
    scatter_k<<<NBLK, 256, 0, stream>>>(pidx, blkbase, perm);

    cvt_k<<<2048, 256, 0, stream>>>(x,  xb,  NT * DIN / 4);
    cvt_k<<<1024, 256, 0, stream>>>(W1, w1b, NPLANES * DHID * DIN / 4);
    cvt_k<<<1024, 256, 0, stream>>>(W2, w2b, NPLANES * DOUT * DHID / 4);

    gemm_k<true ><<<dim3(DHID / 128, 264, 1), 256, 0, stream>>>(
        xb, w1b, b1, perm, offsets, meta, tileP, tileM, (void*)hb);
    gemm_k<false><<<dim3(DOUT / 128, 264, 1), 256, 0, stream>>>(
        hb, w2b, b2, perm, offsets, meta, tileP, tileM, (void*)out);
}